// Round 1
// baseline (194.140 us; speedup 1.0000x reference)
//
#include <hip/hip_runtime.h>
#include <hip/hip_bf16.h>
#include <cstdint>
#include <cstddef>

#define L_SEQ 4096
#define BATCH_N 4
#define HID 1024
#define DH 256
// log2(0.96875)
#define LOG2_GAMMA (-0.045803689613124953f)

typedef __attribute__((ext_vector_type(8))) short short8;
typedef __attribute__((ext_vector_type(4))) float floatx4;

__device__ __forceinline__ unsigned short f2bf(float f) {
    union { float f; unsigned int u; } v; v.f = f;
    unsigned int r = (v.u + 0x7FFFu + ((v.u >> 16) & 1u)) >> 16;  // RNE
    return (unsigned short)r;
}

__device__ __forceinline__ void async_copy16(const unsigned short* gsrc,
                                             unsigned short* lds) {
    __builtin_amdgcn_global_load_lds(
        (const __attribute__((address_space(1))) unsigned int*)gsrc,
        (__attribute__((address_space(3))) unsigned int*)lds, 16, 0, 0);
}

// ---------------------------------------------------------------------------
// Kernel A: X fp32 -> bf16
// ---------------------------------------------------------------------------
__global__ __launch_bounds__(256) void convert_x_kernel(
    const float* __restrict__ X, unsigned short* __restrict__ Xb)
{
    const int i = (blockIdx.x * 256 + threadIdx.x) * 4;
    const float4 v = *(const float4*)&X[i];
    ushort4 p;
    p.x = f2bf(v.x); p.y = f2bf(v.y); p.z = f2bf(v.z); p.w = f2bf(v.w);
    *(ushort4*)&Xb[i] = p;
}

// ---------------------------------------------------------------------------
// Kernel B: W_{Q,K,V} (1024x256 fp32 each) -> Wt bf16 [768][1024] (transposed,
// concatenated: rows 0..255 = Q feats, 256..511 = K, 512..767 = V)
// ---------------------------------------------------------------------------
__global__ __launch_bounds__(256) void transpose_w_kernel(
    const float* __restrict__ WQ, const float* __restrict__ WK,
    const float* __restrict__ WV, unsigned short* __restrict__ Wt)
{
    __shared__ float Ts[64][68];   // [n_local][k_local]
    const int n0 = blockIdx.x * 64;     // 0..704
    const int k0 = blockIdx.y * 64;     // 0..960
    const int seg = n0 >> 8;
    const float* __restrict__ W = (seg == 0) ? WQ : (seg == 1) ? WK : WV;
    const int nl0 = n0 & 255;

    const int t  = threadIdx.x;
    const int r  = t >> 4;          // 0..15
    const int c4 = (t & 15) * 4;
    #pragma unroll
    for (int i = 0; i < 4; ++i) {
        const int kk = r + i * 16;
        const float4 v = *(const float4*)&W[(size_t)(k0 + kk) * DH + nl0 + c4];
        Ts[c4 + 0][kk] = v.x;
        Ts[c4 + 1][kk] = v.y;
        Ts[c4 + 2][kk] = v.z;
        Ts[c4 + 3][kk] = v.w;
    }
    __syncthreads();
    const int rn = t >> 3;          // 0..31
    const int c8 = (t & 7) * 8;
    #pragma unroll
    for (int i = 0; i < 2; ++i) {
        const int rr = rn + i * 32;
        ushort4 p0, p1;
        p0.x = f2bf(Ts[rr][c8 + 0]); p0.y = f2bf(Ts[rr][c8 + 1]);
        p0.z = f2bf(Ts[rr][c8 + 2]); p0.w = f2bf(Ts[rr][c8 + 3]);
        p1.x = f2bf(Ts[rr][c8 + 4]); p1.y = f2bf(Ts[rr][c8 + 5]);
        p1.z = f2bf(Ts[rr][c8 + 6]); p1.w = f2bf(Ts[rr][c8 + 7]);
        unsigned short* dst = &Wt[(size_t)(n0 + rr) * HID + k0 + c8];
        *(ushort4*)dst       = p0;
        *(ushort4*)(dst + 4) = p1;
    }
}

// ---------------------------------------------------------------------------
// Kernel C: QKV projection via bf16 MFMA, output-transposed D[n][pos].
//   1D grid of 768 blocks with XCD-aware remap: dispatch id d -> xcd = d&7,
//   seq = d>>3; each XCD owns 16 consecutive pos-tiles (4 MB Xb = one L2).
// ---------------------------------------------------------------------------
__global__ __launch_bounds__(256) void gemm_qkv_kernel(
    const unsigned short* __restrict__ Wt,   // [768][1024]
    const unsigned short* __restrict__ Xb,   // [16384][1024]
    unsigned short* __restrict__ Qo,
    unsigned short* __restrict__ Ko,
    unsigned short* __restrict__ VtG)
{
    __shared__ unsigned short Wa[128][32];   // 8 KB  [n][k]
    __shared__ unsigned short Xs[128][32];   // 8 KB  [pos][k]

    // XCD swizzle: 768 = 8 xcd * 96; per-XCD 96 blocks = 16 p-tiles x 6 n-tiles
    const int dblk = blockIdx.x;
    const int xcd  = dblk & 7;
    const int sq   = dblk >> 3;        // 0..95
    const int by   = xcd * 16 + sq / 6;
    const int bx   = sq % 6;

    const int n0 = bx * 128;   // 0..640
    const int p0 = by * 128;   // 0..16256
    const int t    = threadIdx.x;
    const int w    = t >> 6;
    const int lane = t & 63;
    const int quad = lane >> 4;
    const int l16  = lane & 15;
    const int wn   = (w & 1) * 64;
    const int wp   = (w >> 1) * 64;

    const int srow = w * 32 + (lane >> 2);   // staging row (+is*16)
    const int scol = (lane & 3) * 8;         // staging col (shorts)

    floatx4 acc[4][4];
    #pragma unroll
    for (int i = 0; i < 4; ++i)
        #pragma unroll
        for (int j = 0; j < 4; ++j) acc[i][j] = (floatx4){0.f, 0.f, 0.f, 0.f};

    for (int k0 = 0; k0 < HID; k0 += 32) {
        __syncthreads();   // previous tile's frag reads complete
        #pragma unroll
        for (int is = 0; is < 2; ++is) {
            const unsigned short* ga =
                &Wt[(size_t)(n0 + srow + is * 16) * HID + k0 + scol];
            const unsigned short* gb =
                &Xb[(size_t)(p0 + srow + is * 16) * HID + k0 + scol];
            async_copy16(ga, &Wa[w * 32 + is * 16][0]);
            async_copy16(gb, &Xs[w * 32 + is * 16][0]);
        }
        __syncthreads();   // staging visible

        short8 af[4], bf[4];
        #pragma unroll
        for (int nt = 0; nt < 4; ++nt)
            af[nt] = *(const short8*)&Wa[wn + nt * 16 + l16][quad * 8];
        #pragma unroll
        for (int pt = 0; pt < 4; ++pt)
            bf[pt] = *(const short8*)&Xs[wp + pt * 16 + l16][quad * 8];
        #pragma unroll
        for (int nt = 0; nt < 4; ++nt)
            #pragma unroll
            for (int pt = 0; pt < 4; ++pt)
                acc[nt][pt] = __builtin_amdgcn_mfma_f32_16x16x32_bf16(
                    af[nt], bf[pt], acc[nt][pt], 0, 0, 0);
    }

    // ---- epilogue ----
    const int seg = n0 >> 8;     // 0=Q 1=K 2=V
    #pragma unroll
    for (int nt = 0; nt < 4; ++nt) {
        const int nfeat = n0 + wn + nt * 16 + quad * 4;  // feat of reg g=0
        const int d0 = nfeat & 255;                      // segment-local
        #pragma unroll
        for (int pt = 0; pt < 4; ++pt) {
            const int pg  = p0 + wp + pt * 16 + l16;     // global row
            const int b   = pg >> 12;
            const int pos = pg & (L_SEQ - 1);
            if (seg == 2) {
                #pragma unroll
                for (int g = 0; g < 4; ++g)
                    VtG[(((size_t)(b * 256 + d0 + g)) << 12) + pos] =
                        f2bf(acc[nt][pt][g]);
            } else {
                const float e = (float)pos * (1.0f / 512.0f);
                float res[4];
                #pragma unroll
                for (int h = 0; h < 4; h += 2) {
                    const int d  = d0 + h;
                    const int i2 = d >> 1;
                    const float sb = ((float)d + 102.4f) * (1.0f / 358.4f);
                    float sc = exp2f(log2f(sb) * e);
                    if (seg == 1) sc = 1.0f / sc;
                    const float invf = exp2f(-13.287712379549449f *
                                             ((float)i2 * (1.0f / 128.0f)));
                    float s, c;
                    sincosf((float)pos * invf, &s, &c);
                    const float cs = c * sc, ss = s * sc;
                    const float xe = acc[nt][pt][h], xo = acc[nt][pt][h + 1];
                    res[h]     = xe * cs - xo * ss;
                    res[h + 1] = xo * cs + xe * ss;
                }
                ushort4 pk;
                pk.x = f2bf(res[0]); pk.y = f2bf(res[1]);
                pk.z = f2bf(res[2]); pk.w = f2bf(res[3]);
                unsigned short* orow =
                    ((seg == 0) ? Qo : Ko) + (size_t)pg * DH + d0;
                *(ushort4*)orow = pk;
            }
        }
    }
}

// ---------------------------------------------------------------------------
// Kernel D: windowed retention via bf16 MFMA.
//   NEW: window split across z=0/1 blocks (512 blocks -> 2 blocks/CU,
//   2 waves/SIMD; LDS 74.5 KB x2 = 149 KB <= 160 KB), 4 independent QK
//   accumulator chains, uint4 V staging, fp32 atomicAdd epilogue into
//   memset-zeroed O (exactly 2 commutative contributions -> deterministic).
// ---------------------------------------------------------------------------
__global__ __launch_bounds__(256) void retention_kernel(
    const unsigned short* __restrict__ Q,
    const unsigned short* __restrict__ K,
    const unsigned short* __restrict__ VtG,
    float* __restrict__ O)
{
    __shared__ short Qs[64][264];
    __shared__ short Ks[32][264];
    __shared__ short Vt[256][40];
    __shared__ short Ss[64][40];

    // XCD swizzle over 512 = 8 xcd * 64: each XCD owns 8 consecutive q-tiles
    // (overlapping decay windows -> K/V L2 locality), all b, both z.
    const int dblk = blockIdx.x;
    const int xcd  = dblk & 7;
    const int sq   = dblk >> 3;           // 0..63
    const int qt   = xcd * 8 + (sq & 7);  // 0..63
    const int b    = (sq >> 3) & 3;
    const int z    = sq >> 5;             // 0 = far half, 1 = near half

    const int t  = threadIdx.x;
    const int q0 = qt * 64;

    const int w    = t >> 6;
    const int lane = t & 63;
    const int quad = lane >> 4;
    const int l16  = lane & 15;
    const int w16  = w * 16;

    const size_t rbase = (size_t)b * L_SEQ * DH;
    const size_t vbase = ((size_t)b * DH) << 12;

    // full window [kst, q0+64); length is always a multiple of 64
    int kst = q0 - 512; if (kst < 0) kst = 0;
    const int half32 = ((q0 + 64 - kst) >> 6) << 5;   // (nsteps/2)*32
    const int kbeg = kst + (z ? half32 : 0);
    const int kfin = z ? (q0 + 64) : (kst + half32);

    {
        const unsigned short* src = Q + rbase + (size_t)q0 * DH;
        #pragma unroll
        for (int i = 0; i < 8; ++i) {
            const int row = i * 8 + (t >> 5);
            const int col = (t & 31) * 8;
            *(uint4*)&Qs[row][col] = *(const uint4*)&src[row * DH + col];
        }
    }

    floatx4 o[16];
    #pragma unroll
    for (int f = 0; f < 16; ++f) o[f] = (floatx4){0.f, 0.f, 0.f, 0.f};

    for (int k0 = kbeg; k0 < kfin; k0 += 32) {
        __syncthreads();
        {
            const unsigned short* src = K + rbase + (size_t)k0 * DH;
            #pragma unroll
            for (int i = 0; i < 4; ++i) {
                const int row = i * 8 + (t >> 5);
                const int col = (t & 31) * 8;
                *(uint4*)&Ks[row][col] = *(const uint4*)&src[row * DH + col];
            }
        }
        {
            const int c0   = t >> 2;
            const int koff = (t & 3) * 8;
            #pragma unroll
            for (int i = 0; i < 4; ++i) {
                const int c = c0 + 64 * i;
                *(uint4*)&Vt[c][koff] =
                    *(const uint4*)&VtG[vbase + ((size_t)c << 12) + k0 + koff];
            }
        }
        __syncthreads();

        // QK^T: 4 independent accumulator chains of length 4
        floatx4 s00 = (floatx4){0.f, 0.f, 0.f, 0.f};
        floatx4 s01 = (floatx4){0.f, 0.f, 0.f, 0.f};
        floatx4 s10 = (floatx4){0.f, 0.f, 0.f, 0.f};
        floatx4 s11 = (floatx4){0.f, 0.f, 0.f, 0.f};
        #pragma unroll
        for (int dd = 0; dd < 4; ++dd) {
            const short8 aA  = *(const short8*)&Qs[w16 + l16][dd * 32 + quad * 8];
            const short8 aB  = *(const short8*)&Qs[w16 + l16][(dd + 4) * 32 + quad * 8];
            const short8 b0A = *(const short8*)&Ks[l16][dd * 32 + quad * 8];
            const short8 b1A = *(const short8*)&Ks[16 + l16][dd * 32 + quad * 8];
            const short8 b0B = *(const short8*)&Ks[l16][(dd + 4) * 32 + quad * 8];
            const short8 b1B = *(const short8*)&Ks[16 + l16][(dd + 4) * 32 + quad * 8];
            s00 = __builtin_amdgcn_mfma_f32_16x16x32_bf16(aA, b0A, s00, 0, 0, 0);
            s10 = __builtin_amdgcn_mfma_f32_16x16x32_bf16(aA, b1A, s10, 0, 0, 0);
            s01 = __builtin_amdgcn_mfma_f32_16x16x32_bf16(aB, b0B, s01, 0, 0, 0);
            s11 = __builtin_amdgcn_mfma_f32_16x16x32_bf16(aB, b1B, s11, 0, 0, 0);
        }
        #pragma unroll
        for (int nt = 0; nt < 2; ++nt) {
            const floatx4 sv = nt ? (s10 + s11) : (s00 + s01);
            const int kpos = k0 + nt * 16 + l16;
            #pragma unroll
            for (int g = 0; g < 4; ++g) {
                const int qpos = q0 + w16 + quad * 4 + g;
                const int dq = qpos - kpos;
                const float p = (dq >= 0) ? sv[g] * exp2f((float)dq * LOG2_GAMMA)
                                          : 0.0f;
                Ss[w16 + quad * 4 + g][nt * 16 + l16] = (short)f2bf(p);
            }
        }
        __syncthreads();

        {
            const short8 a = *(const short8*)&Ss[w16 + l16][quad * 8];
            #pragma unroll
            for (int f = 0; f < 16; ++f) {
                const short8 bfr = *(const short8*)&Vt[f * 16 + l16][quad * 8];
                o[f] = __builtin_amdgcn_mfma_f32_16x16x32_bf16(a, bfr, o[f], 0, 0, 0);
            }
        }
    }

    #pragma unroll
    for (int f = 0; f < 16; ++f) {
        #pragma unroll
        for (int g = 0; g < 4; ++g) {
            const int qpos = q0 + w16 + quad * 4 + g;
            atomicAdd(&O[rbase + (size_t)qpos * DH + f * 16 + l16], o[f][g]);
        }
    }
}

// ---------------------------------------------------------------------------
extern "C" void kernel_launch(void* const* d_in, const int* in_sizes, int n_in,
                              void* d_out, int out_size, void* d_ws, size_t ws_size,
                              hipStream_t stream)
{
    const float* X  = (const float*)d_in[0];
    const float* WQ = (const float*)d_in[1];
    const float* WK = (const float*)d_in[2];
    const float* WV = (const float*)d_in[3];
    float* out = (float*)d_out;

    const size_t per = (size_t)BATCH_N * L_SEQ * DH;   // 4,194,304
    unsigned short* Qw  = (unsigned short*)d_ws;
    unsigned short* Kw  = Qw + per;
    unsigned short* Vtw = Kw + per;
    unsigned short* Xbw = Vtw + per;                   // 16,777,216 elems
    unsigned short* Wtw = Xbw + (size_t)16384 * HID;   // 786,432 elems
    // total workspace: ~60.3 MB

    // O accumulated via atomicAdd from 2 window-half blocks -> zero first
    hipMemsetAsync(out, 0, per * sizeof(float), stream);

    convert_x_kernel<<<16384, 256, 0, stream>>>(X, Xbw);
    transpose_w_kernel<<<dim3(12, 16), 256, 0, stream>>>(WQ, WK, WV, Wtw);

    gemm_qkv_kernel<<<768, 256, 0, stream>>>(Wtw, Xbw, Qw, Kw, Vtw);

    retention_kernel<<<512, 256, 0, stream>>>(Qw, Kw, Vtw, out);
}